// Round 5
// baseline (457.353 us; speedup 1.0000x reference)
//
#include <hip/hip_runtime.h>
#include <hip/hip_bf16.h>

#define KTOP 1000
#define NB 1024
#define CAP 2048
#define MAXOV 0.5f
#define REL1 0.1f
#define REL2 0.05f

typedef unsigned long long u64;
typedef unsigned int u32;

__device__ __forceinline__ const float* pick_scores(const void* A, const void* B, const int* flag) {
    return (*flag) ? (const float*)B : (const float*)A;   // flag=1 -> A is classes
}
__device__ __forceinline__ const int* pick_classes(const void* A, const void* B, const int* flag) {
    return (*flag) ? (const int*)A : (const int*)B;
}

__global__ void idflag_kernel(const u32* __restrict__ A, int* __restrict__ flag) {
    u32 mx = 0;
    for (int i = 0; i < 256; ++i) mx = mx > A[i] ? mx : A[i];
    *flag = (mx < 256u) ? 1 : 0;
}

// ---------------- histogram over score buckets (per batch) ----------------
__global__ __launch_bounds__(256) void hist_kernel(const void* __restrict__ pA,
                                                   const void* __restrict__ pB,
                                                   const int* __restrict__ flag, int N,
                                                   int* __restrict__ hist) {
    __shared__ int h[NB];
    int b = blockIdx.y;
    int t = threadIdx.x;
    for (int i = t; i < NB; i += 256) h[i] = 0;
    __syncthreads();
    const float* s = pick_scores(pA, pB, flag) + (size_t)b * N;
    for (int i = blockIdx.x * 256 + t; i < N; i += gridDim.x * 256) {
        float v = s[i];
        int bu = (int)(v * (float)NB);           // *1024 is exact (pow2) -> monotone bucketing
        bu = bu < 0 ? 0 : (bu > NB - 1 ? NB - 1 : bu);
        atomicAdd(&h[bu], 1);
    }
    __syncthreads();
    int* gh = hist + (size_t)b * NB;
    for (int i = t; i < NB; i += 256) if (h[i]) atomicAdd(&gh[i], h[i]);
}

// ---------------- find cutoff bucket: bucket of the KTOP-th largest score ----------------
__global__ __launch_bounds__(256) void cutoff_kernel(const int* __restrict__ hist,
                                                     int* __restrict__ cutoff) {
    int b = blockIdx.x;
    const int* h = hist + (size_t)b * NB;
    __shared__ int csum[256];
    int t = threadIdx.x;
    int s = 0;
    for (int k = 0; k < NB / 256; ++k) s += h[NB - 1 - t * (NB / 256) - k];
    csum[t] = s;
    __syncthreads();
    if (t == 0) {
        int cum = 0, cut = 0;
        for (int u = 0; u < 256; ++u) {
            if (cum + csum[u] >= KTOP) {
                for (int k = 0; k < NB / 256; ++k) {
                    cum += h[NB - 1 - u * (NB / 256) - k];
                    if (cum >= KTOP) { cut = NB - 1 - u * (NB / 256) - k; break; }
                }
                break;
            }
            cum += csum[u];
        }
        cutoff[b] = cut;
    }
}

// ---------------- collect candidate indices (bucket >= cutoff) ----------------
__global__ __launch_bounds__(256) void collect_kernel(const void* __restrict__ pA,
                                                      const void* __restrict__ pB,
                                                      const int* __restrict__ flag, int N,
                                                      const int* __restrict__ cutoff,
                                                      int* __restrict__ cnt,
                                                      int* __restrict__ cand) {
    int b = blockIdx.y;
    int cut = cutoff[b];
    const float* s = pick_scores(pA, pB, flag) + (size_t)b * N;
    for (int i = blockIdx.x * 256 + threadIdx.x; i < N; i += gridDim.x * 256) {
        float v = s[i];
        int bu = (int)(v * (float)NB);
        bu = bu < 0 ? 0 : (bu > NB - 1 ? NB - 1 : bu);
        if (bu >= cut) {
            int pos = atomicAdd(&cnt[b], 1);
            if (pos < CAP) cand[(size_t)b * CAP + pos] = i;
        }
    }
}

// -------- rank-by-count: exact lax.top_k order (score desc, ties -> lower idx) --------
__global__ __launch_bounds__(1024) void rank_kernel(const void* __restrict__ pA,
                                                    const void* __restrict__ pB,
                                                    const int* __restrict__ flag,
                                                    const float4* __restrict__ boxes, int N,
                                                    const int* __restrict__ cnt,
                                                    const int* __restrict__ cand,
                                                    float* __restrict__ scores_k,
                                                    int* __restrict__ classes_k,
                                                    float4* __restrict__ boxes_k) {
    int b = blockIdx.x, t = threadIdx.x;
    __shared__ u64 key[CAP];
    const float* scores = pick_scores(pA, pB, flag);
    const int* classes = pick_classes(pA, pB, flag);
    int M = cnt[b]; if (M > CAP) M = CAP;
    for (int e = t; e < M; e += 1024) {
        int idx = cand[(size_t)b * CAP + e];
        float s = scores[(size_t)b * N + idx];
        key[e] = ((u64)__float_as_uint(s) << 32) | (u32)(~(u32)idx);
    }
    __syncthreads();
    u64 k0 = (t < M) ? key[t] : 0;
    u64 k1 = (t + 1024 < M) ? key[t + 1024] : 0;
    int r0 = 0, r1 = 0;
    for (int j = 0; j < M; ++j) {
        u64 kj = key[j];                 // LDS broadcast
        r0 += (kj > k0);
        r1 += (kj > k1);
    }
    if (t < M && r0 < KTOP) {
        int idx = (int)(~(u32)k0);
        scores_k[(size_t)b * KTOP + r0] = __uint_as_float((u32)(k0 >> 32));
        classes_k[(size_t)b * KTOP + r0] = classes[(size_t)b * N + idx];
        boxes_k[(size_t)b * KTOP + r0] = boxes[(size_t)b * N + idx];
    }
    if (t + 1024 < M && r1 < KTOP) {
        int idx = (int)(~(u32)k1);
        scores_k[(size_t)b * KTOP + r1] = __uint_as_float((u32)(k1 >> 32));
        classes_k[(size_t)b * KTOP + r1] = classes[(size_t)b * N + idx];
        boxes_k[(size_t)b * KTOP + r1] = boxes[(size_t)b * N + idx];
    }
}

// ---------------- fused: greedy NMS + rel thresholds + compaction + f32 output ----------------
__global__ __launch_bounds__(1024) void nms_kernel(const float* __restrict__ scores_k,
                                                   const int* __restrict__ classes_k,
                                                   const float4* __restrict__ boxes_k,
                                                   float* __restrict__ out, int B) {
    __shared__ float4 sbox[KTOP];
    __shared__ float sscore[KTOP];
    __shared__ int scls[KTOP];
    __shared__ u64 rows[256][16];
    __shared__ u64 keepw[16];
    __shared__ int firstIdx[128];
    __shared__ int wtot[16];

    int b = blockIdx.x;
    int tid = threadIdx.x;
    int lane = tid & 63;
    int wid = tid >> 6;

    for (int i = tid; i < KTOP; i += 1024) {
        sbox[i] = boxes_k[(size_t)b * KTOP + i];
        sscore[i] = scores_k[(size_t)b * KTOP + i];
        scls[i] = classes_k[(size_t)b * KTOP + i];
    }
    __syncthreads();

    u64 sup = 0, keepmask = 0;
    for (int c = 0; c < 4; ++c) {
        for (int task = tid; task < 256 * 16; task += 1024) {
            int r = task >> 4;
            int w = task & 15;
            int i = c * 256 + r;
            u64 bits = 0;
            if (i < KTOP) {
                int j0 = w * 64;
                int j1 = j0 + 64; if (j1 > KTOP) j1 = KTOP;
                int js = (j0 > i + 1) ? j0 : i + 1;
                if (js < j1) {
                    float4 bi = sbox[i];
                    float ai = (bi.z - bi.x) * (bi.w - bi.y);
                    int ci = scls[i];
                    for (int j = js; j < j1; ++j) {
                        if (scls[j] != ci) continue;
                        float4 bj = sbox[j];
                        float xx1 = fmaxf(bi.x, bj.x);
                        float yy1 = fmaxf(bi.y, bj.y);
                        float xx2 = fminf(bi.z, bj.z);
                        float yy2 = fminf(bi.w, bj.w);
                        float ww = xx2 - xx1; ww = ww > 0.f ? ww : 0.f;
                        float hh = yy2 - yy1; hh = hh > 0.f ? hh : 0.f;
                        float inter = ww * hh;
                        float aj = (bj.z - bj.x) * (bj.w - bj.y);
                        float iou = inter / (ai + aj - inter);
                        if (iou > MAXOV) bits |= 1ull << (j - j0);
                    }
                }
            }
            rows[r][w] = bits;
        }
        __syncthreads();
        if (wid == 0) {
            int rmax = KTOP - c * 256; if (rmax > 256) rmax = 256;
            for (int r = 0; r < rmax; ++r) {
                int i = c * 256 + r;
                u64 v = __shfl(sup, i >> 6);
                bool active = ((v >> (i & 63)) & 1ull) == 0ull;
                u64 row = rows[r][lane & 15];
                if (active) {
                    sup |= row;
                    if (lane == (i >> 6)) keepmask |= 1ull << (i & 63);
                }
            }
        }
        __syncthreads();
    }
    if (wid == 0 && lane < 16) keepw[lane] = keepmask;
    if (tid < 128) firstIdx[tid] = 0x7fffffff;
    __syncthreads();

    float s0 = sscore[0];

    for (int i = tid; i < KTOP; i += 1024) {
        bool kp = (keepw[i >> 6] >> (i & 63)) & 1ull;
        if (kp && sscore[i] >= REL1 * s0) atomicMin(&firstIdx[scls[i] & 127], i);
    }
    __syncthreads();

    bool fin = false;
    if (tid < KTOP) {
        bool kp = (keepw[tid >> 6] >> (tid & 63)) & 1ull;
        bool v3 = kp && (sscore[tid] >= REL1 * s0);
        if (v3) {
            int f = firstIdx[scls[tid] & 127];
            bool del = (f < tid) && (sscore[tid] < REL2 * sscore[f]);
            fin = !del;
        }
    }
    u64 m = __ballot(fin);
    if (lane == 0) wtot[wid] = __popcll(m);
    __syncthreads();
    int prefix = 0, V = 0;
    for (int k = 0; k < 16; ++k) { int c = wtot[k]; if (k < wid) prefix += c; V += c; }
    int rank = prefix + __popcll(m & ((1ull << lane) - 1ull));

    float* ob = out;                          // boxes  [B,100,4] f32
    float* oc = out + (size_t)B * 400;        // classes[B,100]  (as float)
    float* os = out + (size_t)B * 500;        // scores [B,100]
    if (fin && rank < 100) {
        int o = b * 100 + rank;
        float4 bx = sbox[tid];
        ob[o * 4 + 0] = bx.x;
        ob[o * 4 + 1] = bx.y;
        ob[o * 4 + 2] = bx.z;
        ob[o * 4 + 3] = bx.w;
        oc[o] = (float)scls[tid];
        os[o] = sscore[tid];
    }
    int Vc = V < 100 ? V : 100;
    if (tid >= Vc && tid < 100) {
        int o = b * 100 + tid;
        ob[o * 4 + 0] = 0.f;
        ob[o * 4 + 1] = 0.f;
        ob[o * 4 + 2] = 0.f;
        ob[o * 4 + 3] = 0.f;
        oc[o] = -1.f;
        os[o] = 0.f;
    }
}

extern "C" void kernel_launch(void* const* d_in, const int* in_sizes, int n_in,
                              void* d_out, int out_size, void* d_ws, size_t ws_size,
                              hipStream_t stream) {
    (void)n_in; (void)ws_size;
    float* out = (float*)d_out;
    int B = out_size / 600;          // 100*(4+1+1) per image

    // identify boxes input purely from sizes (4N vs N); robust to any permutation
    int ib = 0;
    for (int i = 1; i < 3; ++i) if (in_sizes[i] > in_sizes[ib]) ib = i;
    int o1 = -1, o2 = -1;
    for (int i = 0; i < 3; ++i) if (i != ib) { if (o1 < 0) o1 = i; else o2 = i; }
    int N = in_sizes[o1] / B;
    const float4* boxes = (const float4*)d_in[ib];
    const void* pA = d_in[o1];
    const void* pB = d_in[o2];

    char* ws = (char*)d_ws;
    size_t off = 0;
    auto alloc = [&](size_t bytes) { size_t r = off; off += (bytes + 255) & ~(size_t)255; return r; };
    size_t hist_off = alloc((size_t)B * NB * 4);
    size_t cnt_off  = alloc((size_t)B * 4);
    size_t cut_off  = alloc((size_t)B * 4);
    size_t flag_off = alloc(4);
    size_t zero_bytes = off;                     // zero hist + cnt + cutoff + flag each call
    size_t cand_off = alloc((size_t)B * CAP * 4);
    size_t sk_off   = alloc((size_t)B * KTOP * 4);
    size_t ck_off   = alloc((size_t)B * KTOP * 4);
    size_t bk_off   = alloc((size_t)B * KTOP * 16);

    int* hist = (int*)(ws + hist_off);
    int* cnt  = (int*)(ws + cnt_off);
    int* cutf = (int*)(ws + cut_off);
    int* flag = (int*)(ws + flag_off);
    int* cand = (int*)(ws + cand_off);
    float* scores_k = (float*)(ws + sk_off);
    int* classes_k  = (int*)(ws + ck_off);
    float4* boxes_k = (float4*)(ws + bk_off);

    hipMemsetAsync(ws, 0, zero_bytes, stream);
    idflag_kernel<<<1, 1, 0, stream>>>((const u32*)pA, flag);
    hist_kernel<<<dim3(8, B), 256, 0, stream>>>(pA, pB, flag, N, hist);
    cutoff_kernel<<<B, 256, 0, stream>>>(hist, cutf);
    collect_kernel<<<dim3(8, B), 256, 0, stream>>>(pA, pB, flag, N, cutf, cnt, cand);
    rank_kernel<<<B, 1024, 0, stream>>>(pA, pB, flag, boxes, N, cnt, cand,
                                        scores_k, classes_k, boxes_k);
    nms_kernel<<<B, 1024, 0, stream>>>(scores_k, classes_k, boxes_k, out, B);
}

// Round 7
// 204.012 us; speedup vs baseline: 2.2418x; 2.2418x over previous
//
#include <hip/hip_runtime.h>
#include <hip/hip_bf16.h>

#define KTOP 1000
#define NB 1024
#define CAP 2048
#define PCAP 1024
#define REL1 0.1f
#define REL2 0.05f

typedef unsigned long long u64;
typedef unsigned int u32;

__device__ __forceinline__ const float* pick_scores(const void* A, const void* B, const int* flag) {
    return (*flag) ? (const float*)B : (const float*)A;   // flag=1 -> A is classes
}
__device__ __forceinline__ const int* pick_classes(const void* A, const void* B, const int* flag) {
    return (*flag) ? (const int*)A : (const int*)B;
}

// flag=1 iff A looks like int class labels (all bit patterns < 256 over 256 probes)
__global__ __launch_bounds__(256) void idflag_kernel(const u32* __restrict__ A, int* __restrict__ flag) {
    __shared__ int anyBig;
    int t = threadIdx.x;
    if (t == 0) anyBig = 0;
    __syncthreads();
    u32 v = A[t];
    u64 big = __ballot(v >= 256u);
    if ((t & 63) == 0 && big) atomicOr(&anyBig, 1);
    __syncthreads();
    if (t == 0) *flag = anyBig ? 0 : 1;
}

// ---------------- histogram over score buckets (per batch) ----------------
__global__ __launch_bounds__(256) void hist_kernel(const void* __restrict__ pA,
                                                   const void* __restrict__ pB,
                                                   const int* __restrict__ flag, int N,
                                                   int* __restrict__ hist) {
    __shared__ int h[NB];
    int b = blockIdx.y;
    int t = threadIdx.x;
    for (int i = t; i < NB; i += 256) h[i] = 0;
    __syncthreads();
    const float* s = pick_scores(pA, pB, flag) + (size_t)b * N;
    for (int i = blockIdx.x * 256 + t; i < N; i += gridDim.x * 256) {
        float v = s[i];
        int bu = (int)(v * (float)NB);           // *1024 is exact (pow2) -> monotone bucketing
        bu = bu < 0 ? 0 : (bu > NB - 1 ? NB - 1 : bu);
        atomicAdd(&h[bu], 1);
    }
    __syncthreads();
    int* gh = hist + (size_t)b * NB;
    for (int i = t; i < NB; i += 256) if (h[i]) atomicAdd(&gh[i], h[i]);
}

// ---------------- find cutoff bucket: bucket of the KTOP-th largest score ----------------
__global__ __launch_bounds__(256) void cutoff_kernel(const int* __restrict__ hist,
                                                     int* __restrict__ cutoff) {
    int b = blockIdx.x;
    const int* h = hist + (size_t)b * NB;
    __shared__ int csum[256];
    int t = threadIdx.x;
    int s = 0;
    for (int k = 0; k < NB / 256; ++k) s += h[NB - 1 - t * (NB / 256) - k];
    csum[t] = s;
    __syncthreads();
    if (t == 0) {
        int cum = 0, cut = 0;
        for (int u = 0; u < 256; ++u) {
            if (cum + csum[u] >= KTOP) {
                for (int k = 0; k < NB / 256; ++k) {
                    cum += h[NB - 1 - u * (NB / 256) - k];
                    if (cum >= KTOP) { cut = NB - 1 - u * (NB / 256) - k; break; }
                }
                break;
            }
            cum += csum[u];
        }
        cutoff[b] = cut;
    }
}

// ---------------- collect candidates; emit composite keys directly ----------------
__global__ __launch_bounds__(256) void collect_kernel(const void* __restrict__ pA,
                                                      const void* __restrict__ pB,
                                                      const int* __restrict__ flag, int N,
                                                      const int* __restrict__ cutoff,
                                                      int* __restrict__ cnt,
                                                      u64* __restrict__ cand64) {
    int b = blockIdx.y;
    int cut = cutoff[b];
    const float* s = pick_scores(pA, pB, flag) + (size_t)b * N;
    for (int i = blockIdx.x * 256 + threadIdx.x; i < N; i += gridDim.x * 256) {
        float v = s[i];
        int bu = (int)(v * (float)NB);
        bu = bu < 0 ? 0 : (bu > NB - 1 ? NB - 1 : bu);
        if (bu >= cut) {
            int pos = atomicAdd(&cnt[b], 1);
            if (pos < CAP)
                cand64[(size_t)b * CAP + pos] =
                    ((u64)__float_as_uint(v) << 32) | (u32)(~(u32)i);  // score desc, ties -> lower idx
        }
    }
}

// -------- rank-by-count over composite keys; gather top-1000 ----------
__global__ __launch_bounds__(256) void rank_kernel(const void* __restrict__ pA,
                                                   const void* __restrict__ pB,
                                                   const int* __restrict__ flag,
                                                   const float4* __restrict__ boxes, int N,
                                                   const int* __restrict__ cnt,
                                                   const u64* __restrict__ cand64,
                                                   float* __restrict__ scores_k,
                                                   int* __restrict__ classes_k,
                                                   float4* __restrict__ boxes_k) {
    __shared__ u64 key[CAP];
    int b = blockIdx.y, blk = blockIdx.x, tid = threadIdx.x;
    const int* classes = pick_classes(pA, pB, flag);
    int M = cnt[b]; if (M > CAP) M = CAP;
    for (int e = tid; e < M; e += 256) key[e] = cand64[(size_t)b * CAP + e];
    __syncthreads();
    int c = blk * 256 + tid;
    u64 kc = (c < M) ? key[c] : 0;
    int r = 0;
    for (int j = 0; j < M; ++j) r += (key[j] > kc);   // LDS broadcast per j
    if (c < M && r < KTOP) {
        int idx = (int)(~(u32)kc);
        scores_k[(size_t)b * KTOP + r] = __uint_as_float((u32)(kc >> 32));
        classes_k[(size_t)b * KTOP + r] = classes[(size_t)b * N + idx];
        boxes_k[(size_t)b * KTOP + r] = boxes[(size_t)b * N + idx];
    }
}

// ------- fused: class-bucketed pair finding + greedy scan + thresholds + output -------
// Pair sparsity: suppression needs same class; per-class lists cut IoU evals from
// 500k to ~6k per image. Suppressing pairs (expected ~tens, cap 1024) are sorted
// ascending by (i<<10|j); the greedy walk over sorted pairs is equivalent to the
// reference fori_loop because supp bits only flow from i to j>i (keep = ~sup).
__global__ __launch_bounds__(1024) void nmsfinish_kernel(const float* __restrict__ scores_k,
                                                         const int* __restrict__ classes_k,
                                                         const float4* __restrict__ boxes_k,
                                                         float* __restrict__ out, int B) {
    __shared__ float4 sbox[KTOP];      // 16000
    __shared__ float sarea[KTOP];      //  4000
    __shared__ float sscore[KTOP];     //  4000
    __shared__ int scls[KTOP];         //  4000
    __shared__ int myPos[KTOP];        //  4000
    __shared__ short items[KTOP];      //  2000
    __shared__ int clsCnt[128];
    __shared__ int clsStart[128];
    __shared__ u32 pairs[PCAP];        //  4096
    __shared__ u32 sorted[PCAP];       //  4096
    __shared__ int npair;
    __shared__ u64 keepw[16];
    __shared__ int firstIdx[128];
    __shared__ int wtot[16];

    int b = blockIdx.x;
    int tid = threadIdx.x;
    int lane = tid & 63;
    int wid = tid >> 6;

    if (tid < 128) { clsCnt[tid] = 0; firstIdx[tid] = 0x7fffffff; }
    if (tid == 0) npair = 0;
    __syncthreads();

    if (tid < KTOP) {
        float4 bx = boxes_k[(size_t)b * KTOP + tid];
        sbox[tid] = bx;
        sarea[tid] = (bx.z - bx.x) * (bx.w - bx.y);
        sscore[tid] = scores_k[(size_t)b * KTOP + tid];
        int c = classes_k[(size_t)b * KTOP + tid];
        scls[tid] = c;
        myPos[tid] = atomicAdd(&clsCnt[c & 127], 1);
    }
    __syncthreads();
    if (tid == 0) {
        int acc = 0;
        for (int c = 0; c < 128; ++c) { clsStart[c] = acc; acc += clsCnt[c]; }
    }
    __syncthreads();
    if (tid < KTOP) items[clsStart[scls[tid] & 127] + myPos[tid]] = (short)tid;
    __syncthreads();

    // pair finding: thread i scans its class bucket (avg ~12.5 entries)
    if (tid < KTOP) {
        int i = tid;
        float4 bi = sbox[i];
        float ai = sarea[i];
        int ci = scls[i];
        int cb = ci & 127, s = clsStart[cb], n = clsCnt[cb];
        for (int q = 0; q < n; ++q) {
            int j = items[s + q];
            if (j <= i || scls[j] != ci) continue;   // exact class match (bucket may collide)
            float4 bj = sbox[j];
            float xx1 = fmaxf(bi.x, bj.x);
            float yy1 = fmaxf(bi.y, bj.y);
            float xx2 = fminf(bi.z, bj.z);
            float yy2 = fminf(bi.w, bj.w);
            float ww = fmaxf(xx2 - xx1, 0.f);
            float hh = fmaxf(yy2 - yy1, 0.f);
            float inter = ww * hh;
            float iou = inter / (ai + sarea[j] - inter);   // exact reference op order
            if (iou > 0.5f) {
                int p = atomicAdd(&npair, 1);
                if (p < PCAP) pairs[p] = ((u32)i << 10) | (u32)j;
            }
        }
    }
    __syncthreads();

    int P = npair; if (P > PCAP) P = PCAP;
    if (tid < P) {                      // rank-sort ascending; keys unique
        u32 k = pairs[tid];
        int r = 0;
        for (int q = 0; q < P; ++q) r += (pairs[q] < k);
        sorted[r] = k;
    }
    __syncthreads();

    // greedy walk over sorted pairs; wave 0, lane l<16 owns sup word l
    if (wid == 0) {
        u64 sup = 0;
        for (int p = 0; p < P; ++p) {
            u32 k = sorted[p];
            int i = k >> 10;
            u64 supw = __shfl(sup, i >> 6);
            if (((supw >> (i & 63)) & 1ull) == 0ull) {   // i kept -> suppress j
                int j = (int)(k & 1023u);
                if (lane == (j >> 6)) sup |= 1ull << (j & 63);
            }
        }
        if (lane < 16) keepw[lane] = ~sup;
    }
    __syncthreads();

    float s0 = sscore[0];   // index 0 never suppressed (pairs have j>=1); scores descending

    // rel-thresh 2 reduction: first step-3-valid index per class
    for (int i = tid; i < KTOP; i += 1024) {
        bool kp = (keepw[i >> 6] >> (i & 63)) & 1ull;
        if (kp && sscore[i] >= REL1 * s0) atomicMin(&firstIdx[scls[i] & 127], i);
    }
    __syncthreads();

    bool fin = false;
    if (tid < KTOP) {
        bool kp = (keepw[tid >> 6] >> (tid & 63)) & 1ull;
        bool v3 = kp && (sscore[tid] >= REL1 * s0);
        if (v3) {
            int f = firstIdx[scls[tid] & 127];
            bool del = (f < tid) && (sscore[tid] < REL2 * sscore[f]);
            fin = !del;
        }
    }
    u64 m = __ballot(fin);
    if (lane == 0) wtot[wid] = __popcll(m);
    __syncthreads();
    int prefix = 0, V = 0;
    for (int k = 0; k < 16; ++k) { int c = wtot[k]; if (k < wid) prefix += c; V += c; }
    int rank = prefix + __popcll(m & ((1ull << lane) - 1ull));

    float* ob = out;                          // boxes  [B,100,4]
    float* oc = out + (size_t)B * 400;        // classes[B,100] (as float)
    float* os = out + (size_t)B * 500;        // scores [B,100]
    if (fin && rank < 100) {
        int o = b * 100 + rank;
        float4 bx = sbox[tid];
        ob[o * 4 + 0] = bx.x;
        ob[o * 4 + 1] = bx.y;
        ob[o * 4 + 2] = bx.z;
        ob[o * 4 + 3] = bx.w;
        oc[o] = (float)scls[tid];
        os[o] = sscore[tid];
    }
    int Vc = V < 100 ? V : 100;
    if (tid >= Vc && tid < 100) {
        int o = b * 100 + tid;
        ob[o * 4 + 0] = 0.f;
        ob[o * 4 + 1] = 0.f;
        ob[o * 4 + 2] = 0.f;
        ob[o * 4 + 3] = 0.f;
        oc[o] = -1.f;
        os[o] = 0.f;
    }
}

extern "C" void kernel_launch(void* const* d_in, const int* in_sizes, int n_in,
                              void* d_out, int out_size, void* d_ws, size_t ws_size,
                              hipStream_t stream) {
    (void)n_in; (void)ws_size;
    float* out = (float*)d_out;
    int B = out_size / 600;          // 100*(4+1+1) per image

    // identify boxes input purely from sizes (4N vs N); robust to any permutation
    int ib = 0;
    for (int i = 1; i < 3; ++i) if (in_sizes[i] > in_sizes[ib]) ib = i;
    int o1 = -1, o2 = -1;
    for (int i = 0; i < 3; ++i) if (i != ib) { if (o1 < 0) o1 = i; else o2 = i; }
    int N = in_sizes[o1] / B;
    const float4* boxes = (const float4*)d_in[ib];
    const void* pA = d_in[o1];
    const void* pB = d_in[o2];

    char* ws = (char*)d_ws;
    size_t off = 0;
    auto alloc = [&](size_t bytes) { size_t r = off; off += (bytes + 255) & ~(size_t)255; return r; };
    size_t hist_off  = alloc((size_t)B * NB * 4);
    size_t cnt_off   = alloc((size_t)B * 4);
    size_t cut_off   = alloc((size_t)B * 4);
    size_t flag_off  = alloc(4);
    size_t zero_bytes = off;                     // zeroed each call
    size_t cand_off  = alloc((size_t)B * CAP * 8);
    size_t sk_off    = alloc((size_t)B * KTOP * 4);
    size_t ck_off    = alloc((size_t)B * KTOP * 4);
    size_t bk_off    = alloc((size_t)B * KTOP * 16);

    int* hist = (int*)(ws + hist_off);
    int* cnt  = (int*)(ws + cnt_off);
    int* cutf = (int*)(ws + cut_off);
    int* flag = (int*)(ws + flag_off);
    u64* cand64 = (u64*)(ws + cand_off);
    float* scores_k = (float*)(ws + sk_off);
    int* classes_k  = (int*)(ws + ck_off);
    float4* boxes_k = (float4*)(ws + bk_off);

    hipMemsetAsync(ws, 0, zero_bytes, stream);
    idflag_kernel<<<1, 256, 0, stream>>>((const u32*)pA, flag);
    hist_kernel<<<dim3(32, B), 256, 0, stream>>>(pA, pB, flag, N, hist);
    cutoff_kernel<<<B, 256, 0, stream>>>(hist, cutf);
    collect_kernel<<<dim3(32, B), 256, 0, stream>>>(pA, pB, flag, N, cutf, cnt, cand64);
    rank_kernel<<<dim3(8, B), 256, 0, stream>>>(pA, pB, flag, boxes, N, cnt, cand64,
                                                scores_k, classes_k, boxes_k);
    nmsfinish_kernel<<<B, 1024, 0, stream>>>(scores_k, classes_k, boxes_k, out, B);
}

// Round 8
// 62.446 us; speedup vs baseline: 7.3239x; 3.2670x over previous
//
#include <hip/hip_runtime.h>
#include <hip/hip_bf16.h>

#define KTOP 1000
#define NB 1024
#define CAP 2048
#define PCAP 1024
#define REL1 0.1f
#define REL2 0.05f

typedef unsigned long long u64;
typedef unsigned int u32;

__device__ __forceinline__ const float* pick_scores(const void* A, const void* B, const int* flag) {
    return (*flag) ? (const float*)B : (const float*)A;   // flag=1 -> A is classes
}
__device__ __forceinline__ const int* pick_classes(const void* A, const void* B, const int* flag) {
    return (*flag) ? (const int*)A : (const int*)B;
}

__device__ __forceinline__ int bucket_of(float v) {
    int bu = (int)(v * (float)NB);           // *1024 exact (pow2) -> monotone
    return bu < 0 ? 0 : (bu > NB - 1 ? NB - 1 : bu);
}

// flag=1 iff A looks like int class labels (all bit patterns < 256 over 256 probes)
__global__ __launch_bounds__(256) void idflag_kernel(const u32* __restrict__ A, int* __restrict__ flag) {
    __shared__ int anyBig;
    int t = threadIdx.x;
    if (t == 0) anyBig = 0;
    __syncthreads();
    u32 v = A[t];
    u64 big = __ballot(v >= 256u);
    if ((t & 63) == 0 && big) atomicOr(&anyBig, 1);
    __syncthreads();
    if (t == 0) *flag = anyBig ? 0 : 1;
}

// ---------------- histogram over score buckets (per batch), float4 loads ----------------
__global__ __launch_bounds__(256) void hist_kernel(const void* __restrict__ pA,
                                                   const void* __restrict__ pB,
                                                   const int* __restrict__ flag, int N,
                                                   int* __restrict__ hist) {
    __shared__ int h[NB];
    int b = blockIdx.y;
    int t = threadIdx.x;
    for (int i = t; i < NB; i += 256) h[i] = 0;
    __syncthreads();
    const float* s = pick_scores(pA, pB, flag) + (size_t)b * N;
    const float4* s4 = (const float4*)s;
    int N4 = N >> 2;
    for (int i = blockIdx.x * 256 + t; i < N4; i += gridDim.x * 256) {
        float4 v = s4[i];
        atomicAdd(&h[bucket_of(v.x)], 1);
        atomicAdd(&h[bucket_of(v.y)], 1);
        atomicAdd(&h[bucket_of(v.z)], 1);
        atomicAdd(&h[bucket_of(v.w)], 1);
    }
    for (int i = N4 * 4 + blockIdx.x * 256 + t; i < N; i += gridDim.x * 256)
        atomicAdd(&h[bucket_of(s[i])], 1);
    __syncthreads();
    int* gh = hist + (size_t)b * NB;
    for (int i = t; i < NB; i += 256) if (h[i]) atomicAdd(&gh[i], h[i]);
}

// ---------------- find cutoff bucket: bucket of the KTOP-th largest score ----------------
__global__ __launch_bounds__(256) void cutoff_kernel(const int* __restrict__ hist,
                                                     int* __restrict__ cutoff) {
    int b = blockIdx.x;
    const int* h = hist + (size_t)b * NB;
    __shared__ int csum[256];
    int t = threadIdx.x;
    int s = 0;
    for (int k = 0; k < NB / 256; ++k) s += h[NB - 1 - t * (NB / 256) - k];
    csum[t] = s;
    __syncthreads();
    if (t == 0) {
        int cum = 0, cut = 0;
        for (int u = 0; u < 256; ++u) {
            if (cum + csum[u] >= KTOP) {
                for (int k = 0; k < NB / 256; ++k) {
                    cum += h[NB - 1 - u * (NB / 256) - k];
                    if (cum >= KTOP) { cut = NB - 1 - u * (NB / 256) - k; break; }
                }
                break;
            }
            cum += csum[u];
        }
        cutoff[b] = cut;
    }
}

// -------- collect candidates: count -> block prefix -> ONE global atomic/block -> write --------
// (round-7 profile: per-thread atomicAdd on cnt[b] = 2 cachelines contended by all
//  XCDs was 151us. Second pass re-reads ~12.5KB/block: L1-resident.)
__global__ __launch_bounds__(256) void collect_kernel(const void* __restrict__ pA,
                                                      const void* __restrict__ pB,
                                                      const int* __restrict__ flag, int N,
                                                      const int* __restrict__ cutoff,
                                                      int* __restrict__ cnt,
                                                      u64* __restrict__ cand64) {
    __shared__ int pref[256];
    __shared__ int sbase;
    int b = blockIdx.y;
    int t = threadIdx.x;
    int cut = cutoff[b];
    const float* s = pick_scores(pA, pB, flag) + (size_t)b * N;
    const float4* s4 = (const float4*)s;
    int N4 = N >> 2;
    int stride = gridDim.x * 256;

    int nloc = 0;
    for (int i = blockIdx.x * 256 + t; i < N4; i += stride) {
        float4 v = s4[i];
        nloc += (bucket_of(v.x) >= cut) + (bucket_of(v.y) >= cut) +
                (bucket_of(v.z) >= cut) + (bucket_of(v.w) >= cut);
    }
    for (int i = N4 * 4 + blockIdx.x * 256 + t; i < N; i += stride)
        nloc += (bucket_of(s[i]) >= cut);

    pref[t] = nloc;
    __syncthreads();
    if (t == 0) {
        int acc = 0;
        for (int k = 0; k < 256; ++k) { int c = pref[k]; pref[k] = acc; acc += c; }
        sbase = acc ? atomicAdd(&cnt[b], acc) : 0;
    }
    __syncthreads();
    if (nloc == 0) return;

    int pos = sbase + pref[t];
    u64* cb = cand64 + (size_t)b * CAP;
    for (int i = blockIdx.x * 256 + t; i < N4; i += stride) {
        float4 v = s4[i];
        float vv[4] = {v.x, v.y, v.z, v.w};
#pragma unroll
        for (int k = 0; k < 4; ++k) {
            if (bucket_of(vv[k]) >= cut) {
                int idx = i * 4 + k;
                if (pos < CAP)
                    cb[pos] = ((u64)__float_as_uint(vv[k]) << 32) | (u32)(~(u32)idx);
                ++pos;
            }
        }
    }
    for (int i = N4 * 4 + blockIdx.x * 256 + t; i < N; i += stride) {
        float v = s[i];
        if (bucket_of(v) >= cut) {
            if (pos < CAP)
                cb[pos] = ((u64)__float_as_uint(v) << 32) | (u32)(~(u32)i);
            ++pos;
        }
    }
}

// -------- rank-by-count over composite keys; gather top-1000 ----------
__global__ __launch_bounds__(256) void rank_kernel(const void* __restrict__ pA,
                                                   const void* __restrict__ pB,
                                                   const int* __restrict__ flag,
                                                   const float4* __restrict__ boxes, int N,
                                                   const int* __restrict__ cnt,
                                                   const u64* __restrict__ cand64,
                                                   float* __restrict__ scores_k,
                                                   int* __restrict__ classes_k,
                                                   float4* __restrict__ boxes_k) {
    __shared__ u64 key[CAP];
    int b = blockIdx.y, blk = blockIdx.x, tid = threadIdx.x;
    const int* classes = pick_classes(pA, pB, flag);
    int M = cnt[b]; if (M > CAP) M = CAP;
    for (int e = tid; e < M; e += 256) key[e] = cand64[(size_t)b * CAP + e];
    __syncthreads();
    int c = blk * 256 + tid;
    u64 kc = (c < M) ? key[c] : 0;
    int r = 0;
    for (int j = 0; j < M; ++j) r += (key[j] > kc);   // LDS broadcast per j
    if (c < M && r < KTOP) {
        int idx = (int)(~(u32)kc);
        scores_k[(size_t)b * KTOP + r] = __uint_as_float((u32)(kc >> 32));
        classes_k[(size_t)b * KTOP + r] = classes[(size_t)b * N + idx];
        boxes_k[(size_t)b * KTOP + r] = boxes[(size_t)b * N + idx];
    }
}

// ------- fused: class-bucketed pair finding + greedy scan + thresholds + output -------
__global__ __launch_bounds__(1024) void nmsfinish_kernel(const float* __restrict__ scores_k,
                                                         const int* __restrict__ classes_k,
                                                         const float4* __restrict__ boxes_k,
                                                         float* __restrict__ out, int B) {
    __shared__ float4 sbox[KTOP];
    __shared__ float sarea[KTOP];
    __shared__ float sscore[KTOP];
    __shared__ int scls[KTOP];
    __shared__ int myPos[KTOP];
    __shared__ short items[KTOP];
    __shared__ int clsCnt[128];
    __shared__ int clsStart[128];
    __shared__ u32 pairs[PCAP];
    __shared__ u32 sorted[PCAP];
    __shared__ int npair;
    __shared__ u64 keepw[16];
    __shared__ int firstIdx[128];
    __shared__ int wtot[16];

    int b = blockIdx.x;
    int tid = threadIdx.x;
    int lane = tid & 63;
    int wid = tid >> 6;

    if (tid < 128) { clsCnt[tid] = 0; firstIdx[tid] = 0x7fffffff; }
    if (tid == 0) npair = 0;
    __syncthreads();

    if (tid < KTOP) {
        float4 bx = boxes_k[(size_t)b * KTOP + tid];
        sbox[tid] = bx;
        sarea[tid] = (bx.z - bx.x) * (bx.w - bx.y);
        sscore[tid] = scores_k[(size_t)b * KTOP + tid];
        int c = classes_k[(size_t)b * KTOP + tid];
        scls[tid] = c;
        myPos[tid] = atomicAdd(&clsCnt[c & 127], 1);
    }
    __syncthreads();
    if (tid == 0) {
        int acc = 0;
        for (int c = 0; c < 128; ++c) { clsStart[c] = acc; acc += clsCnt[c]; }
    }
    __syncthreads();
    if (tid < KTOP) items[clsStart[scls[tid] & 127] + myPos[tid]] = (short)tid;
    __syncthreads();

    // pair finding: thread i scans its class bucket (avg ~12.5 entries)
    if (tid < KTOP) {
        int i = tid;
        float4 bi = sbox[i];
        float ai = sarea[i];
        int ci = scls[i];
        int cb = ci & 127, s = clsStart[cb], n = clsCnt[cb];
        for (int q = 0; q < n; ++q) {
            int j = items[s + q];
            if (j <= i || scls[j] != ci) continue;
            float4 bj = sbox[j];
            float xx1 = fmaxf(bi.x, bj.x);
            float yy1 = fmaxf(bi.y, bj.y);
            float xx2 = fminf(bi.z, bj.z);
            float yy2 = fminf(bi.w, bj.w);
            float ww = fmaxf(xx2 - xx1, 0.f);
            float hh = fmaxf(yy2 - yy1, 0.f);
            float inter = ww * hh;
            float iou = inter / (ai + sarea[j] - inter);   // exact reference op order
            if (iou > 0.5f) {
                int p = atomicAdd(&npair, 1);
                if (p < PCAP) pairs[p] = ((u32)i << 10) | (u32)j;
            }
        }
    }
    __syncthreads();

    int P = npair; if (P > PCAP) P = PCAP;
    if (tid < P) {                      // rank-sort ascending; keys unique
        u32 k = pairs[tid];
        int r = 0;
        for (int q = 0; q < P; ++q) r += (pairs[q] < k);
        sorted[r] = k;
    }
    __syncthreads();

    // greedy walk over sorted pairs; wave 0, lane l<16 owns sup word l
    if (wid == 0) {
        u64 sup = 0;
        for (int p = 0; p < P; ++p) {
            u32 k = sorted[p];
            int i = k >> 10;
            u64 supw = __shfl(sup, i >> 6);
            if (((supw >> (i & 63)) & 1ull) == 0ull) {   // i kept -> suppress j
                int j = (int)(k & 1023u);
                if (lane == (j >> 6)) sup |= 1ull << (j & 63);
            }
        }
        if (lane < 16) keepw[lane] = ~sup;
    }
    __syncthreads();

    float s0 = sscore[0];   // index 0 never suppressed; scores descending

    for (int i = tid; i < KTOP; i += 1024) {
        bool kp = (keepw[i >> 6] >> (i & 63)) & 1ull;
        if (kp && sscore[i] >= REL1 * s0) atomicMin(&firstIdx[scls[i] & 127], i);
    }
    __syncthreads();

    bool fin = false;
    if (tid < KTOP) {
        bool kp = (keepw[tid >> 6] >> (tid & 63)) & 1ull;
        bool v3 = kp && (sscore[tid] >= REL1 * s0);
        if (v3) {
            int f = firstIdx[scls[tid] & 127];
            bool del = (f < tid) && (sscore[tid] < REL2 * sscore[f]);
            fin = !del;
        }
    }
    u64 m = __ballot(fin);
    if (lane == 0) wtot[wid] = __popcll(m);
    __syncthreads();
    int prefix = 0, V = 0;
    for (int k = 0; k < 16; ++k) { int c = wtot[k]; if (k < wid) prefix += c; V += c; }
    int rank = prefix + __popcll(m & ((1ull << lane) - 1ull));

    float* ob = out;                          // boxes  [B,100,4]
    float* oc = out + (size_t)B * 400;        // classes[B,100] (as float)
    float* os = out + (size_t)B * 500;        // scores [B,100]
    if (fin && rank < 100) {
        int o = b * 100 + rank;
        float4 bx = sbox[tid];
        ob[o * 4 + 0] = bx.x;
        ob[o * 4 + 1] = bx.y;
        ob[o * 4 + 2] = bx.z;
        ob[o * 4 + 3] = bx.w;
        oc[o] = (float)scls[tid];
        os[o] = sscore[tid];
    }
    int Vc = V < 100 ? V : 100;
    if (tid >= Vc && tid < 100) {
        int o = b * 100 + tid;
        ob[o * 4 + 0] = 0.f;
        ob[o * 4 + 1] = 0.f;
        ob[o * 4 + 2] = 0.f;
        ob[o * 4 + 3] = 0.f;
        oc[o] = -1.f;
        os[o] = 0.f;
    }
}

extern "C" void kernel_launch(void* const* d_in, const int* in_sizes, int n_in,
                              void* d_out, int out_size, void* d_ws, size_t ws_size,
                              hipStream_t stream) {
    (void)n_in; (void)ws_size;
    float* out = (float*)d_out;
    int B = out_size / 600;          // 100*(4+1+1) per image

    // identify boxes input purely from sizes (4N vs N); robust to any permutation
    int ib = 0;
    for (int i = 1; i < 3; ++i) if (in_sizes[i] > in_sizes[ib]) ib = i;
    int o1 = -1, o2 = -1;
    for (int i = 0; i < 3; ++i) if (i != ib) { if (o1 < 0) o1 = i; else o2 = i; }
    int N = in_sizes[o1] / B;
    const float4* boxes = (const float4*)d_in[ib];
    const void* pA = d_in[o1];
    const void* pB = d_in[o2];

    char* ws = (char*)d_ws;
    size_t off = 0;
    auto alloc = [&](size_t bytes) { size_t r = off; off += (bytes + 255) & ~(size_t)255; return r; };
    size_t hist_off  = alloc((size_t)B * NB * 4);
    size_t cnt_off   = alloc((size_t)B * 4);
    size_t cut_off   = alloc((size_t)B * 4);
    size_t flag_off  = alloc(4);
    size_t zero_bytes = off;                     // zeroed each call
    size_t cand_off  = alloc((size_t)B * CAP * 8);
    size_t sk_off    = alloc((size_t)B * KTOP * 4);
    size_t ck_off    = alloc((size_t)B * KTOP * 4);
    size_t bk_off    = alloc((size_t)B * KTOP * 16);

    int* hist = (int*)(ws + hist_off);
    int* cnt  = (int*)(ws + cnt_off);
    int* cutf = (int*)(ws + cut_off);
    int* flag = (int*)(ws + flag_off);
    u64* cand64 = (u64*)(ws + cand_off);
    float* scores_k = (float*)(ws + sk_off);
    int* classes_k  = (int*)(ws + ck_off);
    float4* boxes_k = (float4*)(ws + bk_off);

    hipMemsetAsync(ws, 0, zero_bytes, stream);
    idflag_kernel<<<1, 256, 0, stream>>>((const u32*)pA, flag);
    hist_kernel<<<dim3(32, B), 256, 0, stream>>>(pA, pB, flag, N, hist);
    cutoff_kernel<<<B, 256, 0, stream>>>(hist, cutf);
    collect_kernel<<<dim3(32, B), 256, 0, stream>>>(pA, pB, flag, N, cutf, cnt, cand64);
    rank_kernel<<<dim3(8, B), 256, 0, stream>>>(pA, pB, flag, boxes, N, cnt, cand64,
                                                scores_k, classes_k, boxes_k);
    nmsfinish_kernel<<<B, 1024, 0, stream>>>(scores_k, classes_k, boxes_k, out, B);
}

// Round 9
// 58.407 us; speedup vs baseline: 7.8304x; 1.0692x over previous
//
#include <hip/hip_runtime.h>
#include <hip/hip_bf16.h>

#define KTOP 1000
#define NB 1024
#define CAP 2048
#define PCAP 1024
#define HBLK 32            // hist/collect blocks per image
#define REL1 0.1f
#define REL2 0.05f

typedef unsigned long long u64;
typedef unsigned int u32;

__device__ __forceinline__ const float* pick_scores(const void* A, const void* B, int flag) {
    return flag ? (const float*)B : (const float*)A;   // flag=1 -> A is classes
}
__device__ __forceinline__ const int* pick_classes(const void* A, const void* B, int flag) {
    return flag ? (const int*)A : (const int*)B;
}

// flag=1 iff A looks like int class labels (all bit patterns < 256 over 256 probes).
// Computed per-block in LDS; probe loads are L2-hot. Scores ~U[0,1) have bit
// patterns >= ~0x3a800000, so any float-score probe set trips anyBig.
__device__ __forceinline__ int block_flag(const void* pA, int tid, int* ldsf) {
    if (tid == 0) *ldsf = 0;
    __syncthreads();
    if (tid < 256) {
        u32 v = ((const u32*)pA)[tid];
        u64 big = __ballot(v >= 256u);
        if ((tid & 63) == 0 && big) atomicOr(ldsf, 1);
    }
    __syncthreads();
    return *ldsf ? 0 : 1;
}

__device__ __forceinline__ int bucket_of(float v) {
    int bu = (int)(v * (float)NB);           // *1024 exact (pow2) -> monotone
    return bu < 0 ? 0 : (bu > NB - 1 ? NB - 1 : bu);
}

// ---- per-block partial histograms, plain stores (no pre-zero needed) ----
__global__ __launch_bounds__(256) void hist_kernel(const void* __restrict__ pA,
                                                   const void* __restrict__ pB, int N,
                                                   int* __restrict__ phist) {  // [B][HBLK][NB]
    __shared__ int h[NB];
    __shared__ int ldsf;
    int b = blockIdx.y, blk = blockIdx.x;
    int t = threadIdx.x;
    int flag = block_flag(pA, t, &ldsf);
    for (int i = t; i < NB; i += 256) h[i] = 0;
    __syncthreads();
    const float* s = pick_scores(pA, pB, flag) + (size_t)b * N;
    const float4* s4 = (const float4*)s;
    int N4 = N >> 2;
    for (int i = blk * 256 + t; i < N4; i += gridDim.x * 256) {
        float4 v = s4[i];
        atomicAdd(&h[bucket_of(v.x)], 1);
        atomicAdd(&h[bucket_of(v.y)], 1);
        atomicAdd(&h[bucket_of(v.z)], 1);
        atomicAdd(&h[bucket_of(v.w)], 1);
    }
    for (int i = N4 * 4 + blk * 256 + t; i < N; i += gridDim.x * 256)
        atomicAdd(&h[bucket_of(s[i])], 1);
    __syncthreads();
    int4* dst = (int4*)(phist + ((size_t)b * HBLK + blk) * NB);
    dst[t] = make_int4(h[t * 4], h[t * 4 + 1], h[t * 4 + 2], h[t * 4 + 3]);
}

// ---- sum partials, find cutoff bucket of KTOP-th largest score, zero cnt[b] ----
__global__ __launch_bounds__(256) void cutcnt_kernel(const int* __restrict__ phist,
                                                     int* __restrict__ cutoff,
                                                     int* __restrict__ cnt) {
    __shared__ int hh[NB];
    __shared__ int csum[256];
    int b = blockIdx.x, t = threadIdx.x;
    int4 acc = make_int4(0, 0, 0, 0);
    const int4* src = (const int4*)(phist + (size_t)b * HBLK * NB);
    for (int blk = 0; blk < HBLK; ++blk) {
        int4 v = src[blk * 256 + t];     // coalesced 16B per lane
        acc.x += v.x; acc.y += v.y; acc.z += v.z; acc.w += v.w;
    }
    hh[t * 4] = acc.x; hh[t * 4 + 1] = acc.y; hh[t * 4 + 2] = acc.z; hh[t * 4 + 3] = acc.w;
    int s = 0;
    for (int k = 0; k < NB / 256; ++k) s += ((int*)&acc)[(0)] , s = s; // placeholder avoided below
    // suffix-group sums (descending groups of 4), matching original logic
    s = 0;
    {
        int base = NB - 1 - t * (NB / 256);
        s = 0;
#pragma unroll
        for (int k = 0; k < NB / 256; ++k) {
            int idx = base - k;
            int lane4 = idx & 3;
            // hh not yet visible; use acc only if idx in own range. Need syncthreads first.
            (void)lane4;
        }
    }
    __syncthreads();
    {
        int base = NB - 1 - t * (NB / 256);
        int acc2 = 0;
#pragma unroll
        for (int k = 0; k < NB / 256; ++k) acc2 += hh[base - k];
        csum[t] = acc2;
    }
    __syncthreads();
    if (t == 0) {
        int cum = 0, cut = 0;
        for (int u = 0; u < 256; ++u) {
            if (cum + csum[u] >= KTOP) {
                for (int k = 0; k < NB / 256; ++k) {
                    cum += hh[NB - 1 - u * (NB / 256) - k];
                    if (cum >= KTOP) { cut = NB - 1 - u * (NB / 256) - k; break; }
                }
                break;
            }
            cum += csum[u];
        }
        cutoff[b] = cut;
        cnt[b] = 0;                      // replaces host-side memset (stream-ordered)
    }
}

// -------- collect: count -> block prefix -> ONE global atomic/block -> write --------
__global__ __launch_bounds__(256) void collect_kernel(const void* __restrict__ pA,
                                                      const void* __restrict__ pB, int N,
                                                      const int* __restrict__ cutoff,
                                                      int* __restrict__ cnt,
                                                      u64* __restrict__ cand64) {
    __shared__ int pref[256];
    __shared__ int sbase;
    __shared__ int ldsf;
    int b = blockIdx.y;
    int t = threadIdx.x;
    int flag = block_flag(pA, t, &ldsf);
    int cut = cutoff[b];
    const float* s = pick_scores(pA, pB, flag) + (size_t)b * N;
    const float4* s4 = (const float4*)s;
    int N4 = N >> 2;
    int stride = gridDim.x * 256;

    int nloc = 0;
    for (int i = blockIdx.x * 256 + t; i < N4; i += stride) {
        float4 v = s4[i];
        nloc += (bucket_of(v.x) >= cut) + (bucket_of(v.y) >= cut) +
                (bucket_of(v.z) >= cut) + (bucket_of(v.w) >= cut);
    }
    for (int i = N4 * 4 + blockIdx.x * 256 + t; i < N; i += stride)
        nloc += (bucket_of(s[i]) >= cut);

    pref[t] = nloc;
    __syncthreads();
    if (t == 0) {
        int acc = 0;
        for (int k = 0; k < 256; ++k) { int c = pref[k]; pref[k] = acc; acc += c; }
        sbase = acc ? atomicAdd(&cnt[b], acc) : 0;
    }
    __syncthreads();
    if (nloc == 0) return;

    int pos = sbase + pref[t];
    u64* cb = cand64 + (size_t)b * CAP;
    for (int i = blockIdx.x * 256 + t; i < N4; i += stride) {   // L1-resident re-read
        float4 v = s4[i];
        float vv[4] = {v.x, v.y, v.z, v.w};
#pragma unroll
        for (int k = 0; k < 4; ++k) {
            if (bucket_of(vv[k]) >= cut) {
                int idx = i * 4 + k;
                if (pos < CAP)
                    cb[pos] = ((u64)__float_as_uint(vv[k]) << 32) | (u32)(~(u32)idx);
                ++pos;
            }
        }
    }
    for (int i = N4 * 4 + blockIdx.x * 256 + t; i < N; i += stride) {
        float v = s[i];
        if (bucket_of(v) >= cut) {
            if (pos < CAP)
                cb[pos] = ((u64)__float_as_uint(v) << 32) | (u32)(~(u32)i);
            ++pos;
        }
    }
}

// -------- rank-by-count over composite keys; gather top-1000 ----------
__global__ __launch_bounds__(256) void rank_kernel(const void* __restrict__ pA,
                                                   const void* __restrict__ pB,
                                                   const float4* __restrict__ boxes, int N,
                                                   const int* __restrict__ cnt,
                                                   const u64* __restrict__ cand64,
                                                   float* __restrict__ scores_k,
                                                   int* __restrict__ classes_k,
                                                   float4* __restrict__ boxes_k) {
    __shared__ u64 key[CAP];
    __shared__ int ldsf;
    int b = blockIdx.y, blk = blockIdx.x, tid = threadIdx.x;
    int flag = block_flag(pA, tid, &ldsf);
    const int* classes = pick_classes(pA, pB, flag);
    int M = cnt[b]; if (M > CAP) M = CAP;
    for (int e = tid; e < M; e += 256) key[e] = cand64[(size_t)b * CAP + e];
    __syncthreads();
    int c = blk * 256 + tid;
    u64 kc = (c < M) ? key[c] : 0;
    int r = 0;
    for (int j = 0; j < M; ++j) r += (key[j] > kc);   // LDS broadcast per j
    if (c < M && r < KTOP) {
        int idx = (int)(~(u32)kc);
        scores_k[(size_t)b * KTOP + r] = __uint_as_float((u32)(kc >> 32));
        classes_k[(size_t)b * KTOP + r] = classes[(size_t)b * N + idx];
        boxes_k[(size_t)b * KTOP + r] = boxes[(size_t)b * N + idx];
    }
}

// ------- fused: class-bucketed pair finding + greedy scan + thresholds + output -------
__global__ __launch_bounds__(1024) void nmsfinish_kernel(const float* __restrict__ scores_k,
                                                         const int* __restrict__ classes_k,
                                                         const float4* __restrict__ boxes_k,
                                                         float* __restrict__ out, int B) {
    __shared__ float4 sbox[KTOP];
    __shared__ float sarea[KTOP];
    __shared__ float sscore[KTOP];
    __shared__ int scls[KTOP];
    __shared__ int myPos[KTOP];
    __shared__ short items[KTOP];
    __shared__ int clsCnt[128];
    __shared__ int clsStart[128];
    __shared__ u32 pairs[PCAP];
    __shared__ u32 sorted[PCAP];
    __shared__ int npair;
    __shared__ u64 keepw[16];
    __shared__ int firstIdx[128];
    __shared__ int wtot[16];

    int b = blockIdx.x;
    int tid = threadIdx.x;
    int lane = tid & 63;
    int wid = tid >> 6;

    if (tid < 128) { clsCnt[tid] = 0; firstIdx[tid] = 0x7fffffff; }
    if (tid == 0) npair = 0;
    __syncthreads();

    if (tid < KTOP) {
        float4 bx = boxes_k[(size_t)b * KTOP + tid];
        sbox[tid] = bx;
        sarea[tid] = (bx.z - bx.x) * (bx.w - bx.y);
        sscore[tid] = scores_k[(size_t)b * KTOP + tid];
        int c = classes_k[(size_t)b * KTOP + tid];
        scls[tid] = c;
        myPos[tid] = atomicAdd(&clsCnt[c & 127], 1);
    }
    __syncthreads();
    if (tid == 0) {
        int acc = 0;
        for (int c = 0; c < 128; ++c) { clsStart[c] = acc; acc += clsCnt[c]; }
    }
    __syncthreads();
    if (tid < KTOP) items[clsStart[scls[tid] & 127] + myPos[tid]] = (short)tid;
    __syncthreads();

    // pair finding: thread i scans its class bucket (avg ~12.5 entries)
    if (tid < KTOP) {
        int i = tid;
        float4 bi = sbox[i];
        float ai = sarea[i];
        int ci = scls[i];
        int cb = ci & 127, s = clsStart[cb], n = clsCnt[cb];
        for (int q = 0; q < n; ++q) {
            int j = items[s + q];
            if (j <= i || scls[j] != ci) continue;
            float4 bj = sbox[j];
            float xx1 = fmaxf(bi.x, bj.x);
            float yy1 = fmaxf(bi.y, bj.y);
            float xx2 = fminf(bi.z, bj.z);
            float yy2 = fminf(bi.w, bj.w);
            float ww = fmaxf(xx2 - xx1, 0.f);
            float hh = fmaxf(yy2 - yy1, 0.f);
            float inter = ww * hh;
            float iou = inter / (ai + sarea[j] - inter);   // exact reference op order
            if (iou > 0.5f) {
                int p = atomicAdd(&npair, 1);
                if (p < PCAP) pairs[p] = ((u32)i << 10) | (u32)j;
            }
        }
    }
    __syncthreads();

    int P = npair; if (P > PCAP) P = PCAP;
    if (tid < P) {                      // rank-sort ascending; keys unique
        u32 k = pairs[tid];
        int r = 0;
        for (int q = 0; q < P; ++q) r += (pairs[q] < k);
        sorted[r] = k;
    }
    __syncthreads();

    // greedy walk over sorted pairs; wave 0, lane l<16 owns sup word l
    if (wid == 0) {
        u64 sup = 0;
        for (int p = 0; p < P; ++p) {
            u32 k = sorted[p];
            int i = k >> 10;
            u64 supw = __shfl(sup, i >> 6);
            if (((supw >> (i & 63)) & 1ull) == 0ull) {   // i kept -> suppress j
                int j = (int)(k & 1023u);
                if (lane == (j >> 6)) sup |= 1ull << (j & 63);
            }
        }
        if (lane < 16) keepw[lane] = ~sup;
    }
    __syncthreads();

    float s0 = sscore[0];   // index 0 never suppressed; scores descending

    for (int i = tid; i < KTOP; i += 1024) {
        bool kp = (keepw[i >> 6] >> (i & 63)) & 1ull;
        if (kp && sscore[i] >= REL1 * s0) atomicMin(&firstIdx[scls[i] & 127], i);
    }
    __syncthreads();

    bool fin = false;
    if (tid < KTOP) {
        bool kp = (keepw[tid >> 6] >> (tid & 63)) & 1ull;
        bool v3 = kp && (sscore[tid] >= REL1 * s0);
        if (v3) {
            int f = firstIdx[scls[tid] & 127];
            bool del = (f < tid) && (sscore[tid] < REL2 * sscore[f]);
            fin = !del;
        }
    }
    u64 m = __ballot(fin);
    if (lane == 0) wtot[wid] = __popcll(m);
    __syncthreads();
    int prefix = 0, V = 0;
    for (int k = 0; k < 16; ++k) { int c = wtot[k]; if (k < wid) prefix += c; V += c; }
    int rank = prefix + __popcll(m & ((1ull << lane) - 1ull));

    float* ob = out;                          // boxes  [B,100,4]
    float* oc = out + (size_t)B * 400;        // classes[B,100] (as float)
    float* os = out + (size_t)B * 500;        // scores [B,100]
    if (fin && rank < 100) {
        int o = b * 100 + rank;
        float4 bx = sbox[tid];
        ob[o * 4 + 0] = bx.x;
        ob[o * 4 + 1] = bx.y;
        ob[o * 4 + 2] = bx.z;
        ob[o * 4 + 3] = bx.w;
        oc[o] = (float)scls[tid];
        os[o] = sscore[tid];
    }
    int Vc = V < 100 ? V : 100;
    if (tid >= Vc && tid < 100) {
        int o = b * 100 + tid;
        ob[o * 4 + 0] = 0.f;
        ob[o * 4 + 1] = 0.f;
        ob[o * 4 + 2] = 0.f;
        ob[o * 4 + 3] = 0.f;
        oc[o] = -1.f;
        os[o] = 0.f;
    }
}

extern "C" void kernel_launch(void* const* d_in, const int* in_sizes, int n_in,
                              void* d_out, int out_size, void* d_ws, size_t ws_size,
                              hipStream_t stream) {
    (void)n_in; (void)ws_size;
    float* out = (float*)d_out;
    int B = out_size / 600;          // 100*(4+1+1) per image

    // identify boxes input purely from sizes (4N vs N); robust to any permutation
    int ib = 0;
    for (int i = 1; i < 3; ++i) if (in_sizes[i] > in_sizes[ib]) ib = i;
    int o1 = -1, o2 = -1;
    for (int i = 0; i < 3; ++i) if (i != ib) { if (o1 < 0) o1 = i; else o2 = i; }
    int N = in_sizes[o1] / B;
    const float4* boxes = (const float4*)d_in[ib];
    const void* pA = d_in[o1];
    const void* pB = d_in[o2];

    char* ws = (char*)d_ws;
    size_t off = 0;
    auto alloc = [&](size_t bytes) { size_t r = off; off += (bytes + 255) & ~(size_t)255; return r; };
    size_t ph_off    = alloc((size_t)B * HBLK * NB * 4);
    size_t cnt_off   = alloc((size_t)B * 4);
    size_t cut_off   = alloc((size_t)B * 4);
    size_t cand_off  = alloc((size_t)B * CAP * 8);
    size_t sk_off    = alloc((size_t)B * KTOP * 4);
    size_t ck_off    = alloc((size_t)B * KTOP * 4);
    size_t bk_off    = alloc((size_t)B * KTOP * 16);

    int* phist = (int*)(ws + ph_off);
    int* cnt  = (int*)(ws + cnt_off);
    int* cutf = (int*)(ws + cut_off);
    u64* cand64 = (u64*)(ws + cand_off);
    float* scores_k = (float*)(ws + sk_off);
    int* classes_k  = (int*)(ws + ck_off);
    float4* boxes_k = (float4*)(ws + bk_off);

    // no memset: hist partials are plain stores; cnt[b] zeroed by cutcnt_kernel;
    // rank writes all KTOP slots (M >= KTOP by cutoff construction).
    hist_kernel<<<dim3(HBLK, B), 256, 0, stream>>>(pA, pB, N, phist);
    cutcnt_kernel<<<B, 256, 0, stream>>>(phist, cutf, cnt);
    collect_kernel<<<dim3(HBLK, B), 256, 0, stream>>>(pA, pB, N, cutf, cnt, cand64);
    rank_kernel<<<dim3(8, B), 256, 0, stream>>>(pA, pB, boxes, N, cnt, cand64,
                                                scores_k, classes_k, boxes_k);
    nmsfinish_kernel<<<B, 1024, 0, stream>>>(scores_k, classes_k, boxes_k, out, B);
}